// Round 2
// baseline (585.051 us; speedup 1.0000x reference)
//
#include <hip/hip_runtime.h>
#include <hip/hip_bf16.h>

// OuterProduct: out[b, c,    i, j] = |seq1[b,c,i] - seq2[b,c,j]|   (c in [0,64))
//               out[b, 64+c, i, j] =  seq1[b,c,i] * seq2[b,c,j]
// B=8, C=64, L=384. Output [8,128,384,384] fp32 = 604 MB -> write-BW bound.
//
// Mapping: 1 thread = 1 float4 along j. Flat float4 index decomposes exactly
// into (b, c2, i, j4) in output row-major order, so stores are perfectly
// contiguous/coalesced (16 B/lane). Inputs (1.5 MB) are cache-resident.

#define L_DIM 384
#define J4    96      // 384 / 4
#define C_DIM 64

// Native clang vector type: required by __builtin_nontemporal_store
// (HIP_vector_type float4 is a struct and is rejected).
typedef float f4 __attribute__((ext_vector_type(4)));

__global__ __launch_bounds__(256) void outer_product_kernel(
    const float* __restrict__ seq1,
    const float* __restrict__ seq2,
    float* __restrict__ out,
    int n_f4)
{
    int idx = blockIdx.x * 256 + threadIdx.x;
    if (idx >= n_f4) return;

    // idx = ((b*128 + c2)*384 + i)*96 + j4
    int j4 = idx % J4;
    int t  = idx / J4;
    int i  = t % L_DIM;
    int t2 = t / L_DIM;             // t2 = b*128 + c2
    int c  = t2 & (C_DIM - 1);      // channel within [0,64)
    int is_mul = (t2 >> 6) & 1;     // 0: |s1-s2|, 1: s1*s2
    int b  = t2 >> 7;

    int in_row = (b * C_DIM + c) * L_DIM;
    float s1 = seq1[in_row + i];
    f4 s2 = *(const f4*)(seq2 + in_row + j4 * 4);

    f4 o;
    if (is_mul) {
        o = s1 * s2;
    } else {
        f4 d = s1 - s2;
        o.x = fabsf(d.x);
        o.y = fabsf(d.y);
        o.z = fabsf(d.z);
        o.w = fabsf(d.w);
    }

    // Output (604 MB) is never re-read: stream past L2 with non-temporal store.
    __builtin_nontemporal_store(o, (f4*)(out) + idx);
}

extern "C" void kernel_launch(void* const* d_in, const int* in_sizes, int n_in,
                              void* d_out, int out_size, void* d_ws, size_t ws_size,
                              hipStream_t stream)
{
    const float* seq1 = (const float*)d_in[0];
    const float* seq2 = (const float*)d_in[1];
    float* out = (float*)d_out;

    int n_f4 = out_size / 4;                 // 37,748,736
    int grid = (n_f4 + 255) / 256;           // 147,456 blocks
    outer_product_kernel<<<grid, 256, 0, stream>>>(seq1, seq2, out, n_f4);
}